// Round 1
// baseline (20619.606 us; speedup 1.0000x reference)
//
#include <hip/hip_runtime.h>
#include <stdint.h>

typedef __bf16 bf16x8 __attribute__((ext_vector_type(8)));
typedef float f32x4 __attribute__((ext_vector_type(4)));

#define BB 64
#define TT 2048
#define DD 320
#define HH 256
#define NC 10
#define GH 1024  // 4*H

#define GB 4      // batch groups (16 batches each)
#define GJ 32     // j-slices (8 hidden units each)
#define MBATCH 16
#define JW 8      // hidden units per slice
#define NR 32     // gate rows per slice (4*JW)
#define SXS 328   // LDS stride for K=320 tiles (+8 pad -> 2-way bank alias only)
#define SHS 264   // LDS stride for K=256 tiles
#define SGS 33    // gates LDS stride (conflict-free elementwise reads)

__device__ __forceinline__ unsigned short f2bf(float f) {
  unsigned u = __float_as_uint(f);
  u += 0x7FFF + ((u >> 16) & 1);  // round-to-nearest-even
  return (unsigned short)(u >> 16);
}

__global__ void convert_bf16_k(const float* __restrict__ src,
                               unsigned short* __restrict__ dst, int n) {
  int i = blockIdx.x * blockDim.x + threadIdx.x;
  int st = gridDim.x * blockDim.x;
  for (; i < n; i += st) dst[i] = f2bf(src[i]);
}

__global__ void bias_sum_k(const float* __restrict__ a, const float* __restrict__ b,
                           float* __restrict__ d, int n) {
  int i = blockIdx.x * blockDim.x + threadIdx.x;
  if (i < n) d[i] = a[i] + b[i];
}

__device__ __forceinline__ float sigm(float x) { return 1.f / (1.f + __expf(-x)); }
__device__ __forceinline__ float tanh_f(float x) {
  float xx = fminf(fmaxf(x, -15.f), 15.f);
  float e = __expf(2.f * xx);
  return (e - 1.f) / (e + 1.f);
}

// Persistent recurrence kernel. One WG = (batch group gb, j-slice gj).
// Holds W_ih/W_hh slices in LDS across all T steps. Per step:
//   gates[16b x 32rows] = bias + x(t)@Wih^T + h(t-1)@Whh^T   (bf16 MFMA, fp32 acc)
//   c,h elementwise; h slice -> global; release flag; acquire peers' flags.
template <int KX, bool L0>
__launch_bounds__(128)
__global__ void lstm_rec(const unsigned short* __restrict__ xin,  // [B][T][KX] bf16
                         const unsigned short* __restrict__ Wih,  // [GH][KX] bf16
                         const unsigned short* __restrict__ Whh,  // [GH][H]  bf16
                         const float* __restrict__ bias,          // [GH] (b_ih+b_hh)
                         unsigned short* __restrict__ hout,       // L0: [B][T][H] ; else [2][B][H]
                         float* __restrict__ hlast,               // layer1: [B][H] fp32
                         unsigned int* __restrict__ flags)        // [GB*GJ]
{
  __shared__ __align__(16) unsigned short sX[MBATCH * SXS];
  __shared__ __align__(16) unsigned short sH[MBATCH * SHS];
  __shared__ __align__(16) unsigned short sWih[NR * SXS];
  __shared__ __align__(16) unsigned short sWhh[NR * SHS];
  __shared__ float sGates[MBATCH * SGS];
  __shared__ float sBias[NR];

  const int tid = threadIdx.x;
  const int gb = blockIdx.x / GJ;
  const int gj = blockIdx.x % GJ;
  const int j0 = gj * JW;
  const int b0 = gb * MBATCH;

  // ---- stage weight slices (once) ----
  for (int idx = tid; idx < NR * (KX / 8); idx += 128) {
    int r = idx / (KX / 8), c8 = idx % (KX / 8);
    int n = (r / JW) * HH + j0 + (r % JW);
    *(uint4*)&sWih[r * SXS + c8 * 8] = *(const uint4*)&Wih[(size_t)n * KX + c8 * 8];
  }
  for (int idx = tid; idx < NR * (HH / 8); idx += 128) {
    int r = idx / (HH / 8), c8 = idx % (HH / 8);
    int n = (r / JW) * HH + j0 + (r % JW);
    *(uint4*)&sWhh[r * SHS + c8 * 8] = *(const uint4*)&Whh[(size_t)n * HH + c8 * 8];
  }
  if (tid < NR) sBias[tid] = bias[(tid / JW) * HH + j0 + (tid % JW)];

  const int wv = tid >> 6;   // wave 0..1 -> N-tile
  const int ln = tid & 63;
  const int lm = ln & 15;
  const int lq = ln >> 4;

  const int emb = tid >> 3;  // elementwise: batch-in-group 0..15
  const int ejj = tid & 7;   // hidden unit within slice 0..7
  const int bglob = b0 + emb;
  const int jglob = j0 + ejj;
  float c_reg = 0.f;

  __syncthreads();

#pragma unroll 1
  for (int t = 0; t < TT; ++t) {
    // ---- stage x tile (independent of peers) ----
#pragma unroll
    for (int u = 0; u < MBATCH * (KX / 8) / 128; ++u) {
      int idx = tid + u * 128;
      int row = idx / (KX / 8), c8 = idx % (KX / 8);
      *(uint4*)&sX[row * SXS + c8 * 8] =
          *(const uint4*)&xin[((size_t)(b0 + row) * TT + t) * KX + c8 * 8];
    }
    // ---- wait for all peers' h(t-1) ----
    if (t > 0 && tid < GJ) {
      while (__hip_atomic_load(&flags[gb * GJ + tid], __ATOMIC_ACQUIRE,
                               __HIP_MEMORY_SCOPE_AGENT) < (unsigned)t) {}
    }
    __syncthreads();  // S2: x staged + flags seen
    if (t > 0) {
#pragma unroll
      for (int u = 0; u < MBATCH * (HH / 8) / 128; ++u) {
        int idx = tid + u * 128;
        int row = idx / (HH / 8), c8 = idx % (HH / 8);
        size_t src;
        if (L0) src = ((size_t)(b0 + row) * TT + (t - 1)) * HH + c8 * 8;
        else    src = ((size_t)((t - 1) & 1) * BB + (b0 + row)) * HH + c8 * 8;
        *(uint4*)&sH[row * SHS + c8 * 8] = *(const uint4*)&hout[src];
      }
    }
    __syncthreads();  // S3: h staged

    // ---- MFMA: gates = x@Wih^T (+ h@Whh^T), dual accumulators ----
    f32x4 acc0 = {0.f, 0.f, 0.f, 0.f};
    f32x4 acc1 = {0.f, 0.f, 0.f, 0.f};
    {
      const unsigned short* ax = &sX[lm * SXS + lq * 8];
      const unsigned short* bx = &sWih[(wv * 16 + lm) * SXS + lq * 8];
#pragma unroll
      for (int kc = 0; kc < KX / 32; ++kc) {
        bf16x8 a = *(const bf16x8*)(ax + kc * 32);
        bf16x8 b = *(const bf16x8*)(bx + kc * 32);
        if (kc & 1) acc1 = __builtin_amdgcn_mfma_f32_16x16x32_bf16(a, b, acc1, 0, 0, 0);
        else        acc0 = __builtin_amdgcn_mfma_f32_16x16x32_bf16(a, b, acc0, 0, 0, 0);
      }
    }
    if (t > 0) {
      const unsigned short* ah = &sH[lm * SHS + lq * 8];
      const unsigned short* bh = &sWhh[(wv * 16 + lm) * SHS + lq * 8];
#pragma unroll
      for (int kc = 0; kc < HH / 32; ++kc) {
        bf16x8 a = *(const bf16x8*)(ah + kc * 32);
        bf16x8 b = *(const bf16x8*)(bh + kc * 32);
        if (kc & 1) acc1 = __builtin_amdgcn_mfma_f32_16x16x32_bf16(a, b, acc1, 0, 0, 0);
        else        acc0 = __builtin_amdgcn_mfma_f32_16x16x32_bf16(a, b, acc0, 0, 0, 0);
      }
    }
    f32x4 acc = acc0 + acc1;
    float bv = sBias[wv * 16 + lm];
    // D layout (verified m89): col n = lane&15, row m = (lane>>4)*4 + r
#pragma unroll
    for (int r = 0; r < 4; ++r)
      sGates[(lq * 4 + r) * SGS + wv * 16 + lm] = acc[r] + bv;
    __syncthreads();  // S4: gates visible

    // ---- elementwise LSTM cell ----
    {
      float gi = sGates[emb * SGS + 0 * JW + ejj];
      float gf = sGates[emb * SGS + 1 * JW + ejj];
      float gg = sGates[emb * SGS + 2 * JW + ejj];
      float go = sGates[emb * SGS + 3 * JW + ejj];
      float iv = sigm(gi), fv = sigm(gf), gv = tanh_f(gg), ov = sigm(go);
      c_reg = fv * c_reg + iv * gv;
      float hv = ov * tanh_f(c_reg);
      unsigned short hb = f2bf(hv);
      if (L0) {
        hout[((size_t)bglob * TT + t) * HH + jglob] = hb;
      } else {
        hout[((size_t)(t & 1) * BB + bglob) * HH + jglob] = hb;
        if (t == TT - 1) hlast[(size_t)bglob * HH + jglob] = hv;
      }
    }
    __syncthreads();  // S5: all h stores drained (vmcnt(0) before barrier)
    if (tid == 0)
      __hip_atomic_store(&flags[gb * GJ + gj], (unsigned)(t + 1),
                         __ATOMIC_RELEASE, __HIP_MEMORY_SCOPE_AGENT);
  }
}

__global__ void fc_k(const float* __restrict__ h, const float* __restrict__ W,
                     const float* __restrict__ b, float* __restrict__ out) {
  int tid = threadIdx.x;
  if (tid < BB * NC) {
    int bb = tid / NC, cc = tid % NC;
    float s = b[cc];
    for (int j = 0; j < HH; ++j) s += h[bb * HH + j] * W[cc * HH + j];
    out[tid] = s;
  }
}

extern "C" void kernel_launch(void* const* d_in, const int* in_sizes, int n_in,
                              void* d_out, int out_size, void* d_ws, size_t ws_size,
                              hipStream_t stream) {
  (void)in_sizes; (void)n_in; (void)out_size;
  const float* x    = (const float*)d_in[0];
  const float* Wih0 = (const float*)d_in[1];
  const float* Whh0 = (const float*)d_in[2];
  const float* bih0 = (const float*)d_in[3];
  const float* bhh0 = (const float*)d_in[4];
  const float* Wih1 = (const float*)d_in[5];
  const float* Whh1 = (const float*)d_in[6];
  const float* bih1 = (const float*)d_in[7];
  const float* bhh1 = (const float*)d_in[8];
  const float* Wfc  = (const float*)d_in[9];
  const float* bfc  = (const float*)d_in[10];

  char* p = (char*)d_ws;
  size_t off = 0;
  auto alloc = [&](size_t bytes) -> char* {
    char* q = p + off;
    off += (bytes + 255) & ~(size_t)255;
    return q;
  };
  unsigned* flags0 = (unsigned*)alloc(GB * GJ * sizeof(unsigned));   // @0
  unsigned* flags1 = (unsigned*)alloc(GB * GJ * sizeof(unsigned));   // @512
  float* bias0 = (float*)alloc(GH * 4);
  float* bias1 = (float*)alloc(GH * 4);
  unsigned short* Wih0b = (unsigned short*)alloc((size_t)GH * DD * 2);
  unsigned short* Whh0b = (unsigned short*)alloc((size_t)GH * HH * 2);
  unsigned short* Wih1b = (unsigned short*)alloc((size_t)GH * HH * 2);
  unsigned short* Whh1b = (unsigned short*)alloc((size_t)GH * HH * 2);
  unsigned short* h2buf = (unsigned short*)alloc((size_t)2 * BB * HH * 2);
  float* h2last = (float*)alloc((size_t)BB * HH * 4);
  unsigned short* xb  = (unsigned short*)alloc((size_t)BB * TT * DD * 2);
  unsigned short* h1b = (unsigned short*)alloc((size_t)BB * TT * HH * 2);

  if (ws_size < off) return;  // visible failure instead of corruption

  hipMemsetAsync(d_ws, 0, 1024, stream);  // zero both flag arrays
  convert_bf16_k<<<2048, 256, 0, stream>>>(x, xb, BB * TT * DD);
  convert_bf16_k<<<512, 256, 0, stream>>>(Wih0, Wih0b, GH * DD);
  convert_bf16_k<<<512, 256, 0, stream>>>(Whh0, Whh0b, GH * HH);
  convert_bf16_k<<<512, 256, 0, stream>>>(Wih1, Wih1b, GH * HH);
  convert_bf16_k<<<512, 256, 0, stream>>>(Whh1, Whh1b, GH * HH);
  bias_sum_k<<<4, 256, 0, stream>>>(bih0, bhh0, bias0, GH);
  bias_sum_k<<<4, 256, 0, stream>>>(bih1, bhh1, bias1, GH);
  lstm_rec<DD, true ><<<GB * GJ, 128, 0, stream>>>(xb,  Wih0b, Whh0b, bias0, h1b,   nullptr, flags0);
  lstm_rec<HH, false><<<GB * GJ, 128, 0, stream>>>(h1b, Wih1b, Whh1b, bias1, h2buf, h2last,  flags1);
  fc_k<<<1, 640, 0, stream>>>(h2last, Wfc, bfc, (float*)d_out);
}

// Round 2
// 19091.492 us; speedup vs baseline: 1.0800x; 1.0800x over previous
//
#include <hip/hip_runtime.h>
#include <stdint.h>

typedef __bf16 bf16x8 __attribute__((ext_vector_type(8)));
typedef float f32x4 __attribute__((ext_vector_type(4)));
typedef unsigned long long u64;

#define BB 64
#define TT 2048
#define DD 320
#define HH 256
#define NC 10
#define GH 1024  // 4*H

#define GB 4      // batch groups (16 batches each)
#define GJ 8      // j-slice WGs per group (32 hidden units each)
#define MB 16     // batches per group (one M-tile)
#define JW 32     // hidden units per WG
#define NR 128    // gate rows per WG (4*JW)
#define SHS 264   // sH stride in shorts (132 words; 2-way bank alias only = free)
#define SGS 132   // sGates stride in floats
#define NPAIR 2048  // h qwords per (group, parity): MB*HH/2

__device__ __forceinline__ unsigned short f2bf(float f) {
  unsigned u = __float_as_uint(f);
  u += 0x7FFF + ((u >> 16) & 1);  // RNE
  return (unsigned short)(u >> 16);
}

__global__ void convert_bf16_k(const float* __restrict__ src,
                               unsigned short* __restrict__ dst, int n) {
  int i = blockIdx.x * blockDim.x + threadIdx.x;
  int st = gridDim.x * blockDim.x;
  for (; i < n; i += st) dst[i] = f2bf(src[i]);
}

__global__ void bias_sum_k(const float* __restrict__ a, const float* __restrict__ b,
                           float* __restrict__ d, int n) {
  int i = blockIdx.x * blockDim.x + threadIdx.x;
  if (i < n) d[i] = a[i] + b[i];
}

__device__ __forceinline__ float sigm(float x) { return 1.f / (1.f + __expf(-x)); }
__device__ __forceinline__ float tanh_f(float x) {
  float xx = fminf(fmaxf(x, -15.f), 15.f);
  float e = __expf(2.f * xx);
  return (e - 1.f) / (e + 1.f);
}

// Persistent recurrence. One WG per (batch-group gb, j-slice gj), 32 WGs total,
// weights held in VGPRs. h exchange: tagged relaxed agent-scope 8B atomics
// (2 bf16 + tag), parity double-buffered -> NO release/acquire fences, NO L2
// flush/inv per step. Tag protocol ABA-safe: writer reaches step t+1 only
// after reading ALL of h(t), which peers publish only after finishing their
// own reads of h(t-1) (B1 precedes publish in program order).
template <int KX, bool L0>
__launch_bounds__(256, 1)
__global__ void lstm_rec(const unsigned short* __restrict__ xin,  // [B][T][KX] bf16
                         const unsigned short* __restrict__ Wih,  // [GH][KX] bf16
                         const unsigned short* __restrict__ Whh,  // [GH][HH] bf16
                         const float* __restrict__ bias,          // [GH]
                         unsigned short* __restrict__ h1out,      // L0: [B][T][HH] bf16
                         float* __restrict__ hlast,               // L1: [B][HH] f32
                         u64* __restrict__ hx)                    // [GB][2][NPAIR]
{
  constexpr int KCX = KX / 32;     // x-part K-chunks (10 or 8)
  constexpr int KCH = HH / 32;     // h-part K-chunks (8)

  __shared__ __align__(16) unsigned short sH[MB * SHS];
  __shared__ float sG[MB * SGS];   // gates [m=16][n=128] (+pad)

  const int tid = threadIdx.x;
  const int wv = tid >> 6;         // wave 0..3
  const int ln = tid & 63;
  const int lm = ln & 15;
  const int lq = ln >> 4;
  const int gb = blockIdx.x / GJ;
  const int gj = blockIdx.x % GJ;
  const int j0 = gj * JW;
  const int b0 = gb * MB;

  // ---- weights -> registers (once). Wave wv owns N-tiles 2wv, 2wv+1. ----
  bf16x8 bW[2][KCX + KCH];
  float bsv[2];
#pragma unroll
  for (int i = 0; i < 2; ++i) {
    int r = (wv * 2 + i) * 16 + lm;               // local gate-row 0..127
    int grow = (r >> 5) * HH + j0 + (r & 31);     // global gate-row
#pragma unroll
    for (int kc = 0; kc < KCX; ++kc)
      bW[i][kc] = *(const bf16x8*)&Wih[(size_t)grow * KX + kc * 32 + lq * 8];
#pragma unroll
    for (int kc = 0; kc < KCH; ++kc)
      bW[i][KCX + kc] = *(const bf16x8*)&Whh[(size_t)grow * HH + kc * 32 + lq * 8];
    bsv[i] = bias[grow];
  }

  u64* const hxg = hx + (size_t)gb * 2 * NPAIR;
  unsigned* const sHu = (unsigned*)sH;

  // elementwise mapping: thread -> (batch emb, unit pair jp)
  const int emb = tid >> 4;
  const int jp = tid & 15;
  const int jloc = jp * 2;
  const int wpair = emb * (HH / 2) + ((j0 + jloc) >> 1);  // my publish qword
  float c0 = 0.f, c1 = 0.f;

  __syncthreads();

#pragma unroll 1
  for (int t = 0; t < TT; ++t) {
    // ---- issue tagged h(t-1) loads (relaxed, no fences) ----
    u64 q[8];
    const u64* rb = hxg + (size_t)((t + 1) & 1) * NPAIR;  // slot (t-1)&1
    if (t > 0) {
#pragma unroll
      for (int i = 0; i < 8; ++i)
        q[i] = __hip_atomic_load(&rb[i * 256 + tid], __ATOMIC_RELAXED,
                                 __HIP_MEMORY_SCOPE_AGENT);
    }
    // ---- x A-frags global -> reg (cached; nothing invalidates L1/L2 now) ----
    bf16x8 xf[KCX];
#pragma unroll
    for (int kc = 0; kc < KCX; ++kc)
      xf[kc] = *(const bf16x8*)&xin[((size_t)(b0 + lm) * TT + t) * KX + kc * 32 + lq * 8];

    f32x4 acc0 = {0.f, 0.f, 0.f, 0.f};
    f32x4 acc1 = {0.f, 0.f, 0.f, 0.f};
#pragma unroll
    for (int kc = 0; kc < KCX; ++kc) {
      acc0 = __builtin_amdgcn_mfma_f32_16x16x32_bf16(xf[kc], bW[0][kc], acc0, 0, 0, 0);
      acc1 = __builtin_amdgcn_mfma_f32_16x16x32_bf16(xf[kc], bW[1][kc], acc1, 0, 0, 0);
    }

    if (t > 0) {
      // ---- spin on tags, strip, stage to LDS ----
      const unsigned expct = (unsigned)t;
#pragma unroll
      for (int i = 0; i < 8; ++i) {
        int sp = 0;
        while ((unsigned)(q[i] >> 32) != expct) {
          ++sp;
          q[i] = ((sp & 63) == 63)
                     ? __hip_atomic_load(&rb[i * 256 + tid], __ATOMIC_ACQUIRE,
                                         __HIP_MEMORY_SCOPE_AGENT)
                     : __hip_atomic_load(&rb[i * 256 + tid], __ATOMIC_RELAXED,
                                         __HIP_MEMORY_SCOPE_AGENT);
        }
        int w = i * 256 + tid;
        sHu[(w >> 7) * (SHS / 2) + (w & 127)] = (unsigned)q[i];
      }
      __syncthreads();  // B1: sH ready
#pragma unroll
      for (int kc = 0; kc < KCH; ++kc) {
        bf16x8 a = *(const bf16x8*)&sH[lm * SHS + kc * 32 + lq * 8];
        acc0 = __builtin_amdgcn_mfma_f32_16x16x32_bf16(a, bW[0][KCX + kc], acc0, 0, 0, 0);
        acc1 = __builtin_amdgcn_mfma_f32_16x16x32_bf16(a, bW[1][KCX + kc], acc1, 0, 0, 0);
      }
    }

    // ---- D -> sGates (D: m = lq*4+r, n = lane&15 within tile; verified R0) ----
#pragma unroll
    for (int r = 0; r < 4; ++r) {
      sG[(lq * 4 + r) * SGS + (wv * 2 + 0) * 16 + lm] = acc0[r] + bsv[0];
      sG[(lq * 4 + r) * SGS + (wv * 2 + 1) * 16 + lm] = acc1[r] + bsv[1];
    }
    __syncthreads();  // B2: gates ready

    // ---- elementwise cell (2 units/thread) ----
    {
      const float* gp = &sG[emb * SGS];
      float i0 = gp[0 * JW + jloc], i1 = gp[0 * JW + jloc + 1];
      float f0 = gp[1 * JW + jloc], f1 = gp[1 * JW + jloc + 1];
      float g0 = gp[2 * JW + jloc], g1 = gp[2 * JW + jloc + 1];
      float o0 = gp[3 * JW + jloc], o1 = gp[3 * JW + jloc + 1];
      c0 = sigm(f0) * c0 + sigm(i0) * tanh_f(g0);
      c1 = sigm(f1) * c1 + sigm(i1) * tanh_f(g1);
      float h0 = sigm(o0) * tanh_f(c0);
      float h1 = sigm(o1) * tanh_f(c1);
      unsigned pair = (unsigned)f2bf(h0) | ((unsigned)f2bf(h1) << 16);
      u64 val = ((u64)(unsigned)(t + 1) << 32) | pair;
      __hip_atomic_store(&hxg[(size_t)(t & 1) * NPAIR + wpair], val,
                         __ATOMIC_RELAXED, __HIP_MEMORY_SCOPE_AGENT);
      if (L0) {
        ((unsigned*)h1out)[((size_t)(b0 + emb) * TT + t) * (HH / 2) + ((j0 + jloc) >> 1)] = pair;
      } else if (t == TT - 1) {
        hlast[(size_t)(b0 + emb) * HH + j0 + jloc] = h0;
        hlast[(size_t)(b0 + emb) * HH + j0 + jloc + 1] = h1;
      }
    }
  }
}

__global__ void fc_k(const float* __restrict__ h, const float* __restrict__ W,
                     const float* __restrict__ b, float* __restrict__ out) {
  int tid = threadIdx.x;
  if (tid < BB * NC) {
    int bb = tid / NC, cc = tid % NC;
    float s = b[cc];
    for (int j = 0; j < HH; ++j) s += h[bb * HH + j] * W[cc * HH + j];
    out[tid] = s;
  }
}

extern "C" void kernel_launch(void* const* d_in, const int* in_sizes, int n_in,
                              void* d_out, int out_size, void* d_ws, size_t ws_size,
                              hipStream_t stream) {
  (void)in_sizes; (void)n_in; (void)out_size;
  const float* x    = (const float*)d_in[0];
  const float* Wih0 = (const float*)d_in[1];
  const float* Whh0 = (const float*)d_in[2];
  const float* bih0 = (const float*)d_in[3];
  const float* bhh0 = (const float*)d_in[4];
  const float* Wih1 = (const float*)d_in[5];
  const float* Whh1 = (const float*)d_in[6];
  const float* bih1 = (const float*)d_in[7];
  const float* bhh1 = (const float*)d_in[8];
  const float* Wfc  = (const float*)d_in[9];
  const float* bfc  = (const float*)d_in[10];

  char* p = (char*)d_ws;
  size_t off = 0;
  auto alloc = [&](size_t bytes) -> char* {
    char* q = p + off;
    off += (bytes + 255) & ~(size_t)255;
    return q;
  };
  u64* hx0 = (u64*)alloc((size_t)GB * 2 * NPAIR * 8);  // tagged h exchange, L0
  u64* hx1 = (u64*)alloc((size_t)GB * 2 * NPAIR * 8);  // tagged h exchange, L1
  float* bias0 = (float*)alloc(GH * 4);
  float* bias1 = (float*)alloc(GH * 4);
  unsigned short* Wih0b = (unsigned short*)alloc((size_t)GH * DD * 2);
  unsigned short* Whh0b = (unsigned short*)alloc((size_t)GH * HH * 2);
  unsigned short* Wih1b = (unsigned short*)alloc((size_t)GH * HH * 2);
  unsigned short* Whh1b = (unsigned short*)alloc((size_t)GH * HH * 2);
  float* h2last = (float*)alloc((size_t)BB * HH * 4);
  unsigned short* xb  = (unsigned short*)alloc((size_t)BB * TT * DD * 2);
  unsigned short* h1b = (unsigned short*)alloc((size_t)BB * TT * HH * 2);

  if (ws_size < off) return;

  // No flag init needed: 0xAA poison / zeros never match a valid tag (1..TT).
  convert_bf16_k<<<2048, 256, 0, stream>>>(x, xb, BB * TT * DD);
  convert_bf16_k<<<512, 256, 0, stream>>>(Wih0, Wih0b, GH * DD);
  convert_bf16_k<<<512, 256, 0, stream>>>(Whh0, Whh0b, GH * HH);
  convert_bf16_k<<<512, 256, 0, stream>>>(Wih1, Wih1b, GH * HH);
  convert_bf16_k<<<512, 256, 0, stream>>>(Whh1, Whh1b, GH * HH);
  bias_sum_k<<<4, 256, 0, stream>>>(bih0, bhh0, bias0, GH);
  bias_sum_k<<<4, 256, 0, stream>>>(bih1, bhh1, bias1, GH);
  lstm_rec<DD, true ><<<GB * GJ, 256, 0, stream>>>(xb,  Wih0b, Whh0b, bias0, h1b, nullptr, hx0);
  lstm_rec<HH, false><<<GB * GJ, 256, 0, stream>>>(h1b, Wih1b, Whh1b, bias1, nullptr, h2last, hx1);
  fc_k<<<1, 640, 0, stream>>>(h2last, Wfc, bfc, (float*)d_out);
}

// Round 3
// 8770.824 us; speedup vs baseline: 2.3509x; 2.1767x over previous
//
#include <hip/hip_runtime.h>
#include <stdint.h>

typedef __bf16 bf16x8 __attribute__((ext_vector_type(8)));
typedef float f32x4 __attribute__((ext_vector_type(4)));
typedef unsigned long long u64;

#define BB 64
#define TT 2048
#define DD 320
#define HH 256
#define NC 10
#define GH 1024  // 4*H

#define GB 4         // batch groups (16 batches each)
#define GJ 4         // j-slice WGs per group (64 hidden units each)
#define MB 16        // batches per group (one M-tile)
#define JW 64        // hidden units per WG
#define NTHREADS 512 // 8 waves
#define SHS 264      // shorts stride for 16x256 bf16 LDS tiles (132 dwords)
#define SGS 260      // floats stride for gates tile
#define NPAIR 2048   // MB*HH/2 qwords per (group, parity)
#define NPT 4        // NPAIR / NTHREADS qwords polled per thread

__device__ __forceinline__ unsigned short f2bf(float f) {
  unsigned u = __float_as_uint(f);
  u += 0x7FFF + ((u >> 16) & 1);  // RNE
  return (unsigned short)(u >> 16);
}

__global__ void convert_bf16_k(const float* __restrict__ src,
                               unsigned short* __restrict__ dst, int n) {
  int i = blockIdx.x * blockDim.x + threadIdx.x;
  int st = gridDim.x * blockDim.x;
  for (; i < n; i += st) dst[i] = f2bf(src[i]);
}

__global__ void bias_sum_k(const float* __restrict__ a, const float* __restrict__ b,
                           float* __restrict__ d, int n) {
  int i = blockIdx.x * blockDim.x + threadIdx.x;
  if (i < n) d[i] = a[i] + b[i];
}

__device__ __forceinline__ float sigm(float x) { return 1.f / (1.f + __expf(-x)); }
__device__ __forceinline__ float tanh_f(float x) {
  float xx = fminf(fmaxf(x, -15.f), 15.f);
  float e = __expf(2.f * xx);
  return (e - 1.f) / (e + 1.f);
}

__device__ __forceinline__ u64 ald(const u64* p) {
  return __hip_atomic_load(p, __ATOMIC_RELAXED, __HIP_MEMORY_SCOPE_AGENT);
}
__device__ __forceinline__ void ast(u64* p, u64 v) {
  __hip_atomic_store(p, v, __ATOMIC_RELAXED, __HIP_MEMORY_SCOPE_AGENT);
}

// One layer-role body. Tagged relaxed 8B atomics (2 bf16 + step tag) for all
// cross-WG data: no fences ever. Parity double-buffer for own-layer h
// exchange (ABA-safe: writer reaches slot reuse only after all readers
// consumed, via the peer-publish dependency chain). L0 additionally publishes
// h1(t) into a write-once tagged [B][T][H/2] buffer that L1 polls as input.
template <int KCX, bool IS_L0>
__device__ __forceinline__ void lstm_role(
    const unsigned short* __restrict__ xin,  // L0: x bf16 [B][T][KCX*32]
    const u64* __restrict__ xtag,            // L1: tagged h1 [B][T][HH/2]
    const unsigned short* __restrict__ Wih,  // [GH][KCX*32] bf16
    const unsigned short* __restrict__ Whh,  // [GH][HH] bf16
    const float* __restrict__ bias,          // [GH]
    u64* __restrict__ h1out,                 // L0 publish target
    float* __restrict__ hlast,               // L1: [B][HH] f32
    u64* __restrict__ hx,                    // whole-layer exchange [GB][2][NPAIR]
    unsigned short* sX, unsigned short* sH, float* sG,
    int gb, int gj)
{
  constexpr int KX = KCX * 32;
  constexpr int KCH = HH / 32;   // 8
  constexpr int KCT = KCX + KCH;

  const int tid = threadIdx.x;
  const int wv = tid >> 6;       // wave 0..7 -> N-tiles 2wv, 2wv+1
  const int ln = tid & 63;
  const int lm = ln & 15;
  const int lq = ln >> 4;
  const int j0 = gj * JW;
  const int b0 = gb * MB;

  // ---- weights -> registers/AGPRs (once) ----
  bf16x8 bW[2][KCT];
  float bsv[2];
#pragma unroll
  for (int i = 0; i < 2; ++i) {
    int r = (wv * 2 + i) * 16 + lm;            // local gate-row 0..255
    int grow = (r >> 6) * HH + j0 + (r & 63);  // global gate-row
#pragma unroll
    for (int kc = 0; kc < KCX; ++kc)
      bW[i][kc] = *(const bf16x8*)&Wih[(size_t)grow * KX + kc * 32 + lq * 8];
#pragma unroll
    for (int kc = 0; kc < KCH; ++kc)
      bW[i][KCX + kc] = *(const bf16x8*)&Whh[(size_t)grow * HH + kc * 32 + lq * 8];
    bsv[i] = bias[grow];
  }

  u64* const hxg = hx + (size_t)gb * 2 * NPAIR;
  unsigned* const sHu = (unsigned*)sH;
  unsigned* const sXu = (unsigned*)sX;

  const int emb = tid >> 5;           // batch 0..15
  const int jp = tid & 31;            // unit pair 0..31
  const int jloc = jp * 2;
  const int wpair = emb * (HH / 2) + ((j0 + jloc) >> 1);
  float c0 = 0.f, c1 = 0.f;

  __syncthreads();

#pragma unroll 1
  for (int t = 0; t < TT; ++t) {
    // ---- L0: x A-frags FIRST (so x-MFMA wait doesn't drain exchange loads) ----
    bf16x8 xf[IS_L0 ? KCX : 1];
    if (IS_L0) {
#pragma unroll
      for (int kc = 0; kc < KCX; ++kc)
        xf[kc] = *(const bf16x8*)&xin[((size_t)(b0 + lm) * TT + t) * KX + kc * 32 + lq * 8];
    }
    // ---- issue tagged loads ----
    u64 qh[NPT], qx[NPT];
    u64* const rb = hxg + (size_t)((t + 1) & 1) * NPAIR;  // slot (t-1)&1
    const u64* xr = nullptr;
    if (!IS_L0) {
      xr = xtag + ((size_t)b0 * TT + t) * (HH / 2);  // +m*TT*HH/2 per word below
#pragma unroll
      for (int i = 0; i < NPT; ++i) {
        int w = i * NTHREADS + tid;
        qx[i] = ald(&xr[(size_t)(w >> 7) * TT * (HH / 2) + (w & 127)]);
      }
    }
    if (t > 0) {
#pragma unroll
      for (int i = 0; i < NPT; ++i) qh[i] = ald(&rb[i * NTHREADS + tid]);
    }

    f32x4 acc0 = {0.f, 0.f, 0.f, 0.f};
    f32x4 acc1 = {0.f, 0.f, 0.f, 0.f};
    if (IS_L0) {
#pragma unroll
      for (int kc = 0; kc < KCX; ++kc) {
        acc0 = __builtin_amdgcn_mfma_f32_16x16x32_bf16(xf[kc], bW[0][kc], acc0, 0, 0, 0);
        acc1 = __builtin_amdgcn_mfma_f32_16x16x32_bf16(xf[kc], bW[1][kc], acc1, 0, 0, 0);
      }
    }

    // ---- batched spin: every retry reloads ALL pending words in parallel ----
    {
      const unsigned etx = (unsigned)(t + 1), eth = (unsigned)t;
      bool ok;
      do {
        ok = true;
        if (!IS_L0) {
#pragma unroll
          for (int i = 0; i < NPT; ++i) ok &= ((unsigned)(qx[i] >> 32) == etx);
        }
        if (t > 0) {
#pragma unroll
          for (int i = 0; i < NPT; ++i) ok &= ((unsigned)(qh[i] >> 32) == eth);
        }
        if (!ok) {
          if (!IS_L0) {
#pragma unroll
            for (int i = 0; i < NPT; ++i) {
              int w = i * NTHREADS + tid;
              qx[i] = ald(&xr[(size_t)(w >> 7) * TT * (HH / 2) + (w & 127)]);
            }
          }
          if (t > 0) {
#pragma unroll
            for (int i = 0; i < NPT; ++i) qh[i] = ald(&rb[i * NTHREADS + tid]);
          }
        }
      } while (!ok);
    }

    // ---- stage to LDS ----
    if (!IS_L0) {
#pragma unroll
      for (int i = 0; i < NPT; ++i) {
        int w = i * NTHREADS + tid;
        sXu[(w >> 7) * (SHS / 2) + (w & 127)] = (unsigned)qx[i];
      }
    }
    if (t > 0) {
#pragma unroll
      for (int i = 0; i < NPT; ++i) {
        int w = i * NTHREADS + tid;
        sHu[(w >> 7) * (SHS / 2) + (w & 127)] = (unsigned)qh[i];
      }
    }
    __syncthreads();  // B1

    if (!IS_L0) {
#pragma unroll
      for (int kc = 0; kc < KCX; ++kc) {
        bf16x8 a = *(const bf16x8*)&sX[lm * SHS + kc * 32 + lq * 8];
        acc0 = __builtin_amdgcn_mfma_f32_16x16x32_bf16(a, bW[0][kc], acc0, 0, 0, 0);
        acc1 = __builtin_amdgcn_mfma_f32_16x16x32_bf16(a, bW[1][kc], acc1, 0, 0, 0);
      }
    }
    if (t > 0) {
#pragma unroll
      for (int kc = 0; kc < KCH; ++kc) {
        bf16x8 a = *(const bf16x8*)&sH[lm * SHS + kc * 32 + lq * 8];
        acc0 = __builtin_amdgcn_mfma_f32_16x16x32_bf16(a, bW[0][KCX + kc], acc0, 0, 0, 0);
        acc1 = __builtin_amdgcn_mfma_f32_16x16x32_bf16(a, bW[1][KCX + kc], acc1, 0, 0, 0);
      }
    }

    // D layout: m = lq*4+r, n = lane&15 (verified)
#pragma unroll
    for (int r = 0; r < 4; ++r) {
      sG[(lq * 4 + r) * SGS + (wv * 2 + 0) * 16 + lm] = acc0[r] + bsv[0];
      sG[(lq * 4 + r) * SGS + (wv * 2 + 1) * 16 + lm] = acc1[r] + bsv[1];
    }
    __syncthreads();  // B2

    // ---- elementwise cell: 2 units/thread ----
    {
      const float* gp = &sG[emb * SGS];
      float gi0 = gp[0 * JW + jloc], gi1 = gp[0 * JW + jloc + 1];
      float gf0 = gp[1 * JW + jloc], gf1 = gp[1 * JW + jloc + 1];
      float gg0 = gp[2 * JW + jloc], gg1 = gp[2 * JW + jloc + 1];
      float go0 = gp[3 * JW + jloc], go1 = gp[3 * JW + jloc + 1];
      c0 = sigm(gf0) * c0 + sigm(gi0) * tanh_f(gg0);
      c1 = sigm(gf1) * c1 + sigm(gi1) * tanh_f(gg1);
      float h0 = sigm(go0) * tanh_f(c0);
      float h1 = sigm(go1) * tanh_f(c1);
      unsigned pair = (unsigned)f2bf(h0) | ((unsigned)f2bf(h1) << 16);
      u64 val = ((u64)(unsigned)(t + 1) << 32) | pair;
      ast(&hxg[(size_t)(t & 1) * NPAIR + wpair], val);
      if (IS_L0) {
        ast(&h1out[((size_t)(b0 + emb) * TT + t) * (HH / 2) + ((j0 + jloc) >> 1)], val);
      } else if (t == TT - 1) {
        hlast[(size_t)(b0 + emb) * HH + j0 + jloc] = h0;
        hlast[(size_t)(b0 + emb) * HH + j0 + jloc + 1] = h1;
      }
    }
  }
}

__launch_bounds__(NTHREADS, 2)
__global__ void lstm_fused(const unsigned short* __restrict__ xb,
                           u64* __restrict__ h1tag,
                           const unsigned short* __restrict__ Wih0,
                           const unsigned short* __restrict__ Whh0,
                           const float* __restrict__ bias0,
                           const unsigned short* __restrict__ Wih1,
                           const unsigned short* __restrict__ Whh1,
                           const float* __restrict__ bias1,
                           float* __restrict__ h2last,
                           u64* __restrict__ hx0, u64* __restrict__ hx1) {
  __shared__ __align__(16) unsigned short sX[MB * SHS];
  __shared__ __align__(16) unsigned short sH[MB * SHS];
  __shared__ __align__(16) float sG[MB * SGS];
  const int role = blockIdx.x >> 4;
  const int rid = blockIdx.x & 15;
  const int gb = rid >> 2, gj = rid & 3;
  if (role == 0)
    lstm_role<DD / 32, true>(xb, nullptr, Wih0, Whh0, bias0, h1tag, nullptr,
                             hx0, sX, sH, sG, gb, gj);
  else
    lstm_role<HH / 32, false>(nullptr, h1tag, Wih1, Whh1, bias1, nullptr,
                              h2last, hx1, sX, sH, sG, gb, gj);
}

__global__ void fc_k(const float* __restrict__ h, const float* __restrict__ W,
                     const float* __restrict__ b, float* __restrict__ out) {
  int tid = threadIdx.x;
  if (tid < BB * NC) {
    int bb = tid / NC, cc = tid % NC;
    float s = b[cc];
    for (int j = 0; j < HH; ++j) s += h[bb * HH + j] * W[cc * HH + j];
    out[tid] = s;
  }
}

extern "C" void kernel_launch(void* const* d_in, const int* in_sizes, int n_in,
                              void* d_out, int out_size, void* d_ws, size_t ws_size,
                              hipStream_t stream) {
  (void)in_sizes; (void)n_in; (void)out_size;
  const float* x    = (const float*)d_in[0];
  const float* Wih0 = (const float*)d_in[1];
  const float* Whh0 = (const float*)d_in[2];
  const float* bih0 = (const float*)d_in[3];
  const float* bhh0 = (const float*)d_in[4];
  const float* Wih1 = (const float*)d_in[5];
  const float* Whh1 = (const float*)d_in[6];
  const float* bih1 = (const float*)d_in[7];
  const float* bhh1 = (const float*)d_in[8];
  const float* Wfc  = (const float*)d_in[9];
  const float* bfc  = (const float*)d_in[10];

  char* p = (char*)d_ws;
  size_t off = 0;
  auto alloc = [&](size_t bytes) -> char* {
    char* q = p + off;
    off += (bytes + 255) & ~(size_t)255;
    return q;
  };
  u64* hx0 = (u64*)alloc((size_t)GB * 2 * NPAIR * 8);
  u64* hx1 = (u64*)alloc((size_t)GB * 2 * NPAIR * 8);
  float* bias0 = (float*)alloc(GH * 4);
  float* bias1 = (float*)alloc(GH * 4);
  unsigned short* Wih0b = (unsigned short*)alloc((size_t)GH * DD * 2);
  unsigned short* Whh0b = (unsigned short*)alloc((size_t)GH * HH * 2);
  unsigned short* Wih1b = (unsigned short*)alloc((size_t)GH * HH * 2);
  unsigned short* Whh1b = (unsigned short*)alloc((size_t)GH * HH * 2);
  float* h2last = (float*)alloc((size_t)BB * HH * 4);
  unsigned short* xb = (unsigned short*)alloc((size_t)BB * TT * DD * 2);
  u64* h1tag = (u64*)alloc((size_t)BB * TT * (HH / 2) * 8);

  if (ws_size < off) return;  // visible failure instead of corruption

  // Tags: 0xAAAAAAAA poison never matches any expected tag in [1,2048].
  convert_bf16_k<<<2048, 256, 0, stream>>>(x, xb, BB * TT * DD);
  convert_bf16_k<<<512, 256, 0, stream>>>(Wih0, Wih0b, GH * DD);
  convert_bf16_k<<<512, 256, 0, stream>>>(Whh0, Whh0b, GH * HH);
  convert_bf16_k<<<512, 256, 0, stream>>>(Wih1, Wih1b, GH * HH);
  convert_bf16_k<<<512, 256, 0, stream>>>(Whh1, Whh1b, GH * HH);
  bias_sum_k<<<4, 256, 0, stream>>>(bih0, bhh0, bias0, GH);
  bias_sum_k<<<4, 256, 0, stream>>>(bih1, bhh1, bias1, GH);
  lstm_fused<<<GB * GJ * 2, NTHREADS, 0, stream>>>(
      xb, h1tag, Wih0b, Whh0b, bias0, Wih1b, Whh1b, bias1, h2last, hx0, hx1);
  fc_k<<<1, 640, 0, stream>>>(h2last, Wfc, bfc, (float*)d_out);
}

// Round 4
// 7150.613 us; speedup vs baseline: 2.8836x; 1.2266x over previous
//
#include <hip/hip_runtime.h>
#include <stdint.h>

typedef __bf16 bf16x8 __attribute__((ext_vector_type(8)));
typedef float f32x4 __attribute__((ext_vector_type(4)));
typedef unsigned long long u64;

#define BB 64
#define TT 2048
#define DD 320
#define HH 256
#define NC 10
#define GH 1024  // 4*H

#define GB 4         // batch groups (16 batches each)
#define GJ 4         // j-slice WGs per group (64 hidden units each)
#define MB 16        // batches per group
#define JW 64        // hidden units per WG
#define NTHREADS 512 // 8 waves
#define SHS 264      // shorts stride for 16x256 bf16 LDS tiles
#define SGS 260      // floats stride for gates tile
#define NPAIR 2048   // MB*HH/2 qwords per (group, parity)
#define NPT 4        // qx words per thread (L1 input)
#define NRW 3        // remote hx words per thread (own slice excluded)

__device__ __forceinline__ unsigned short f2bf(float f) {
  unsigned u = __float_as_uint(f);
  u += 0x7FFF + ((u >> 16) & 1);  // RNE
  return (unsigned short)(u >> 16);
}

__global__ void convert_bf16_k(const float* __restrict__ src,
                               unsigned short* __restrict__ dst, int n) {
  int i = blockIdx.x * blockDim.x + threadIdx.x;
  int st = gridDim.x * blockDim.x;
  for (; i < n; i += st) dst[i] = f2bf(src[i]);
}

__global__ void bias_sum_k(const float* __restrict__ a, const float* __restrict__ b,
                           float* __restrict__ d, int n) {
  int i = blockIdx.x * blockDim.x + threadIdx.x;
  if (i < n) d[i] = a[i] + b[i];
}

__device__ __forceinline__ float sigm(float x) { return 1.f / (1.f + __expf(-x)); }
__device__ __forceinline__ float tanh_s(float x) { return 2.f * sigm(2.f * x) - 1.f; }

__device__ __forceinline__ u64 ald(const u64* p) {
  return __hip_atomic_load(p, __ATOMIC_RELAXED, __HIP_MEMORY_SCOPE_AGENT);
}
__device__ __forceinline__ void ast(u64* p, u64 v) {
  __hip_atomic_store(p, v, __ATOMIC_RELAXED, __HIP_MEMORY_SCOPE_AGENT);
}

// Persistent fused 2-layer LSTM recurrence. Tagged relaxed 8B atomics
// (2 bf16 | step tag) carry all cross-WG data; no fences ever.
// R3: input prefetch one step ahead; 4 MFMA acc chains/wave; own h-slice
// kept in LDS (polls cover remote 3/4 only); retry reloads failing stream only.
template <int KCX, bool IS_L0>
__device__ __forceinline__ void lstm_role(
    const unsigned short* __restrict__ xin,  // L0: x bf16 [B][T][KCX*32]
    const u64* __restrict__ xtag,            // L1: tagged h1 [B][T][HH/2]
    const unsigned short* __restrict__ Wih,
    const unsigned short* __restrict__ Whh,
    const float* __restrict__ bias,
    u64* __restrict__ h1out,                 // L0 publish target
    float* __restrict__ hlast,               // L1: [B][HH] f32
    u64* __restrict__ hx,                    // [GB][2][NPAIR]
    unsigned short* sX, unsigned short* sH, float* sG,
    int gb, int gj)
{
  constexpr int KX = KCX * 32;
  constexpr int KCH = HH / 32;  // 8

  const int tid = threadIdx.x;
  const int wv = tid >> 6;
  const int ln = tid & 63;
  const int lm = ln & 15;
  const int lq = ln >> 4;
  const int j0 = gj * JW;
  const int b0 = gb * MB;

  // ---- weights -> registers/AGPRs (once) ----
  bf16x8 bW[2][KCX + KCH];
  float bsv[2];
#pragma unroll
  for (int i = 0; i < 2; ++i) {
    int r = (wv * 2 + i) * 16 + lm;            // local gate-row 0..255
    int grow = (r >> 6) * HH + j0 + (r & 63);  // global gate-row
#pragma unroll
    for (int kc = 0; kc < KCX; ++kc)
      bW[i][kc] = *(const bf16x8*)&Wih[(size_t)grow * KX + kc * 32 + lq * 8];
#pragma unroll
    for (int kc = 0; kc < KCH; ++kc)
      bW[i][KCX + kc] = *(const bf16x8*)&Whh[(size_t)grow * HH + kc * 32 + lq * 8];
    bsv[i] = bias[grow];
  }

  // ---- remote hx word ids (3/thread, own slice excluded) ----
  int rw[NRW];
#pragma unroll
  for (int i = 0; i < NRW; ++i) {
    int rp = i * NTHREADS + tid;   // 0..1535
    int em = rp / 96;
    int q = rp - em * 96;
    int pe = q >> 5;
    pe += (pe >= gj);              // skip own peer slot
    rw[i] = em * 128 + pe * 32 + (q & 31);
  }

  u64* const hxg = hx + (size_t)gb * 2 * NPAIR;
  unsigned* const sHu = (unsigned*)sH;
  unsigned* const sXu = (unsigned*)sX;

  const int emb = tid >> 5;       // batch 0..15
  const int jp = tid & 31;        // unit pair 0..31
  const int jloc = jp * 2;
  const int wpair = emb * 128 + (j0 >> 1) + jp;
  float c0 = 0.f, c1 = 0.f;

  // ---- preamble prefetch for t=0 ----
  bf16x8 xf[IS_L0 ? KCX : 1];
  u64 qx[NPT];
  if (IS_L0) {
#pragma unroll
    for (int kc = 0; kc < KCX; ++kc)
      xf[kc] = *(const bf16x8*)&xin[((size_t)(b0 + lm) * TT + 0) * KX + kc * 32 + lq * 8];
  } else {
#pragma unroll
    for (int i = 0; i < NPT; ++i) {
      int w = i * NTHREADS + tid;
      qx[i] = ald(&xtag[((size_t)(b0 + (w >> 7)) * TT + 0) * 128 + (w & 127)]);
    }
  }

  __syncthreads();

#pragma unroll 1
  for (int t = 0; t < TT; ++t) {
    u64* const rb = hxg + (size_t)((t + 1) & 1) * NPAIR;  // slot (t-1)&1
    u64 qh[NRW];
    if (t > 0) {
#pragma unroll
      for (int i = 0; i < NRW; ++i) qh[i] = ald(&rb[rw[i]]);
    }

    f32x4 ac[2][2] = {{{0.f, 0.f, 0.f, 0.f}, {0.f, 0.f, 0.f, 0.f}},
                      {{0.f, 0.f, 0.f, 0.f}, {0.f, 0.f, 0.f, 0.f}}};
    if (IS_L0) {
      // x-part immediately from prefetched regs (overlaps qh flight)
#pragma unroll
      for (int kc = 0; kc < KCX; ++kc) {
        ac[0][kc & 1] = __builtin_amdgcn_mfma_f32_16x16x32_bf16(xf[kc], bW[0][kc], ac[0][kc & 1], 0, 0, 0);
        ac[1][kc & 1] = __builtin_amdgcn_mfma_f32_16x16x32_bf16(xf[kc], bW[1][kc], ac[1][kc & 1], 0, 0, 0);
      }
    }

    // ---- spin (reload only the failing stream) ----
    {
      const unsigned etx = (unsigned)(t + 1), eth = (unsigned)t;
      bool ok;
      do {
        bool okx = true, okh = true;
        if (!IS_L0) {
#pragma unroll
          for (int i = 0; i < NPT; ++i) okx &= ((unsigned)(qx[i] >> 32) == etx);
        }
        if (t > 0) {
#pragma unroll
          for (int i = 0; i < NRW; ++i) okh &= ((unsigned)(qh[i] >> 32) == eth);
        }
        ok = okx && okh;
        if (!ok) {
          if (!IS_L0 && !okx) {
#pragma unroll
            for (int i = 0; i < NPT; ++i) {
              int w = i * NTHREADS + tid;
              qx[i] = ald(&xtag[((size_t)(b0 + (w >> 7)) * TT + t) * 128 + (w & 127)]);
            }
          }
          if (t > 0 && !okh) {
#pragma unroll
            for (int i = 0; i < NRW; ++i) qh[i] = ald(&rb[rw[i]]);
          }
        }
      } while (!ok);
    }

    // ---- stage to LDS (remote h only; own slice already written) ----
    if (!IS_L0) {
#pragma unroll
      for (int i = 0; i < NPT; ++i) {
        int w = i * NTHREADS + tid;
        sXu[(w >> 7) * (SHS / 2) + (w & 127)] = (unsigned)qx[i];
      }
    }
    if (t > 0) {
#pragma unroll
      for (int i = 0; i < NRW; ++i)
        sHu[(rw[i] >> 7) * (SHS / 2) + (rw[i] & 127)] = (unsigned)qh[i];
    }
    __syncthreads();  // B1

    // ---- prefetch inputs for t+1 (overlaps MFMA + elementwise) ----
    if (t + 1 < TT) {
      if (IS_L0) {
#pragma unroll
        for (int kc = 0; kc < KCX; ++kc)
          xf[kc] = *(const bf16x8*)&xin[((size_t)(b0 + lm) * TT + (t + 1)) * KX + kc * 32 + lq * 8];
      } else {
#pragma unroll
        for (int i = 0; i < NPT; ++i) {
          int w = i * NTHREADS + tid;
          qx[i] = ald(&xtag[((size_t)(b0 + (w >> 7)) * TT + (t + 1)) * 128 + (w & 127)]);
        }
      }
    }

    if (!IS_L0) {
#pragma unroll
      for (int kc = 0; kc < KCX; ++kc) {
        bf16x8 a = *(const bf16x8*)&sX[lm * SHS + kc * 32 + lq * 8];
        ac[0][kc & 1] = __builtin_amdgcn_mfma_f32_16x16x32_bf16(a, bW[0][kc], ac[0][kc & 1], 0, 0, 0);
        ac[1][kc & 1] = __builtin_amdgcn_mfma_f32_16x16x32_bf16(a, bW[1][kc], ac[1][kc & 1], 0, 0, 0);
      }
    }
    if (t > 0) {
#pragma unroll
      for (int kc = 0; kc < KCH; ++kc) {
        bf16x8 a = *(const bf16x8*)&sH[lm * SHS + kc * 32 + lq * 8];
        ac[0][kc & 1] = __builtin_amdgcn_mfma_f32_16x16x32_bf16(a, bW[0][KCX + kc], ac[0][kc & 1], 0, 0, 0);
        ac[1][kc & 1] = __builtin_amdgcn_mfma_f32_16x16x32_bf16(a, bW[1][KCX + kc], ac[1][kc & 1], 0, 0, 0);
      }
    }

    f32x4 A0 = ac[0][0] + ac[0][1];
    f32x4 A1 = ac[1][0] + ac[1][1];
    // D layout: m = lq*4+r, n = lane&15 (verified)
#pragma unroll
    for (int r = 0; r < 4; ++r) {
      sG[(lq * 4 + r) * SGS + (wv * 2 + 0) * 16 + lm] = A0[r] + bsv[0];
      sG[(lq * 4 + r) * SGS + (wv * 2 + 1) * 16 + lm] = A1[r] + bsv[1];
    }
    __syncthreads();  // B2

    // ---- elementwise cell: 2 units/thread; publish ASAP ----
    {
      const float* gp = &sG[emb * SGS];
      float gi0 = gp[0 * JW + jloc], gi1 = gp[0 * JW + jloc + 1];
      float gf0 = gp[1 * JW + jloc], gf1 = gp[1 * JW + jloc + 1];
      float gg0 = gp[2 * JW + jloc], gg1 = gp[2 * JW + jloc + 1];
      float go0 = gp[3 * JW + jloc], go1 = gp[3 * JW + jloc + 1];
      c0 = sigm(gf0) * c0 + sigm(gi0) * tanh_s(gg0);
      c1 = sigm(gf1) * c1 + sigm(gi1) * tanh_s(gg1);
      float h0 = sigm(go0) * tanh_s(c0);
      float h1 = sigm(go1) * tanh_s(c1);
      unsigned pair = (unsigned)f2bf(h0) | ((unsigned)f2bf(h1) << 16);
      u64 val = ((u64)(unsigned)(t + 1) << 32) | pair;
      ast(&hxg[(size_t)(t & 1) * NPAIR + wpair], val);           // own-layer exchange first
      sHu[emb * (SHS / 2) + (j0 >> 1) + jp] = pair;              // own slice -> LDS (no IF trip)
      if (IS_L0) {
        ast(&h1out[((size_t)(b0 + emb) * TT + t) * 128 + (j0 >> 1) + jp], val);
      } else if (t == TT - 1) {
        hlast[(size_t)(b0 + emb) * HH + j0 + jloc] = h0;
        hlast[(size_t)(b0 + emb) * HH + j0 + jloc + 1] = h1;
      }
    }
  }
}

__launch_bounds__(NTHREADS, 1)
__global__ void lstm_fused(const unsigned short* __restrict__ xb,
                           u64* __restrict__ h1tag,
                           const unsigned short* __restrict__ Wih0,
                           const unsigned short* __restrict__ Whh0,
                           const float* __restrict__ bias0,
                           const unsigned short* __restrict__ Wih1,
                           const unsigned short* __restrict__ Whh1,
                           const float* __restrict__ bias1,
                           float* __restrict__ h2last,
                           u64* __restrict__ hx0, u64* __restrict__ hx1) {
  __shared__ __align__(16) unsigned short sX[MB * SHS];
  __shared__ __align__(16) unsigned short sH[MB * SHS];
  __shared__ __align__(16) float sG[MB * SGS];
  const int role = blockIdx.x >> 4;
  const int rid = blockIdx.x & 15;
  const int gb = rid >> 2, gj = rid & 3;
  if (role == 0)
    lstm_role<DD / 32, true>(xb, nullptr, Wih0, Whh0, bias0, h1tag, nullptr,
                             hx0, sX, sH, sG, gb, gj);
  else
    lstm_role<HH / 32, false>(nullptr, h1tag, Wih1, Whh1, bias1, nullptr,
                              h2last, hx1, sX, sH, sG, gb, gj);
}

__global__ void fc_k(const float* __restrict__ h, const float* __restrict__ W,
                     const float* __restrict__ b, float* __restrict__ out) {
  int tid = threadIdx.x;
  if (tid < BB * NC) {
    int bb = tid / NC, cc = tid % NC;
    float s = b[cc];
    for (int j = 0; j < HH; ++j) s += h[bb * HH + j] * W[cc * HH + j];
    out[tid] = s;
  }
}

extern "C" void kernel_launch(void* const* d_in, const int* in_sizes, int n_in,
                              void* d_out, int out_size, void* d_ws, size_t ws_size,
                              hipStream_t stream) {
  (void)in_sizes; (void)n_in; (void)out_size;
  const float* x    = (const float*)d_in[0];
  const float* Wih0 = (const float*)d_in[1];
  const float* Whh0 = (const float*)d_in[2];
  const float* bih0 = (const float*)d_in[3];
  const float* bhh0 = (const float*)d_in[4];
  const float* Wih1 = (const float*)d_in[5];
  const float* Whh1 = (const float*)d_in[6];
  const float* bih1 = (const float*)d_in[7];
  const float* bhh1 = (const float*)d_in[8];
  const float* Wfc  = (const float*)d_in[9];
  const float* bfc  = (const float*)d_in[10];

  char* p = (char*)d_ws;
  size_t off = 0;
  auto alloc = [&](size_t bytes) -> char* {
    char* q = p + off;
    off += (bytes + 255) & ~(size_t)255;
    return q;
  };
  u64* hx0 = (u64*)alloc((size_t)GB * 2 * NPAIR * 8);
  u64* hx1 = (u64*)alloc((size_t)GB * 2 * NPAIR * 8);
  float* bias0 = (float*)alloc(GH * 4);
  float* bias1 = (float*)alloc(GH * 4);
  unsigned short* Wih0b = (unsigned short*)alloc((size_t)GH * DD * 2);
  unsigned short* Whh0b = (unsigned short*)alloc((size_t)GH * HH * 2);
  unsigned short* Wih1b = (unsigned short*)alloc((size_t)GH * HH * 2);
  unsigned short* Whh1b = (unsigned short*)alloc((size_t)GH * HH * 2);
  float* h2last = (float*)alloc((size_t)BB * HH * 4);
  unsigned short* xb = (unsigned short*)alloc((size_t)BB * TT * DD * 2);
  u64* h1tag = (u64*)alloc((size_t)BB * TT * (HH / 2) * 8);

  if (ws_size < off) return;  // visible failure instead of corruption

  // Tags: 0xAAAAAAAA poison never matches any expected tag in [1,2048].
  convert_bf16_k<<<2048, 256, 0, stream>>>(x, xb, BB * TT * DD);
  convert_bf16_k<<<512, 256, 0, stream>>>(Wih0, Wih0b, GH * DD);
  convert_bf16_k<<<512, 256, 0, stream>>>(Whh0, Whh0b, GH * HH);
  convert_bf16_k<<<512, 256, 0, stream>>>(Wih1, Wih1b, GH * HH);
  convert_bf16_k<<<512, 256, 0, stream>>>(Whh1, Whh1b, GH * HH);
  bias_sum_k<<<4, 256, 0, stream>>>(bih0, bhh0, bias0, GH);
  bias_sum_k<<<4, 256, 0, stream>>>(bih1, bhh1, bias1, GH);
  lstm_fused<<<GB * GJ * 2, NTHREADS, 0, stream>>>(
      xb, h1tag, Wih0b, Whh0b, bias0, Wih1b, Whh1b, bias1, h2last, hx0, hx1);
  fc_k<<<1, 640, 0, stream>>>(h2last, Wfc, bfc, (float*)d_out);
}